// Round 1
// baseline (293.361 us; speedup 1.0000x reference)
//
#include <hip/hip_runtime.h>
#include <stdint.h>

// MemoryAugmentedLayer: B=32768, D=256, M=1024, K=V=128.
// Restructured: logits = kvec @ (KM^T @ W) instead of (kvec @ KM^T) @ W.
// All big GEMMs in bf16 MFMA 16x16x32, fp32 accumulate.

typedef short bf16x8 __attribute__((ext_vector_type(8)));
typedef float f32x4  __attribute__((ext_vector_type(4)));

#define MFMA(a, b, c) __builtin_amdgcn_mfma_f32_16x16x32_bf16((a), (b), (c), 0, 0, 0)

__device__ __forceinline__ short f2bf(float f) {
    union { float f; uint32_t u; } v; v.f = f;
    uint32_t r = (v.u + 0x7FFFu + ((v.u >> 16) & 1u)) >> 16;
    return (short)r;
}
__device__ __forceinline__ float bf2f(short h) {
    union { uint32_t u; float f; } v; v.u = ((uint32_t)(uint16_t)h) << 16;
    return v.f;
}
__device__ __forceinline__ uint32_t pack2(float a, float b) {
    return (uint32_t)(uint16_t)f2bf(a) | ((uint32_t)(uint16_t)f2bf(b) << 16);
}

// ---------------------------------------------------------------------------
// Wt[c][d] = bf16(W{k,v,q}[d][c&127]),  c in [0,384), d in [0,256)
__global__ void kw_kernel(const float* __restrict__ Wk, const float* __restrict__ Wv,
                          const float* __restrict__ Wq, short* __restrict__ wt) {
    const int c = blockIdx.x;       // 0..383
    const int d = threadIdx.x;      // 0..255
    const float* W = (c < 128) ? Wk : ((c < 256) ? Wv : Wq);
    wt[c * 256 + d] = f2bf(W[d * 128 + (c & 127)]);
}

// ---------------------------------------------------------------------------
// kvq[b][0:384] = elu(x @ [Wk|Wv|Wq] + [bk|bv|bq]) in bf16.
// Block: 64 rows, 4 waves; wave w owns cols [w*96, w*96+96).
__global__ __launch_bounds__(256) void proj_kernel(
    const float* __restrict__ x, const short* __restrict__ wt,
    const float* __restrict__ bk, const float* __restrict__ bv,
    const float* __restrict__ bq, short* __restrict__ kvq)
{
    const int tid = threadIdx.x;
    const int wave = tid >> 6, lane = tid & 63;
    const int l15 = lane & 15, lq = lane >> 4;
    const int r0 = blockIdx.x * 64;

    f32x4 acc[4][6];
    for (int i = 0; i < 4; ++i)
        for (int j = 0; j < 6; ++j) acc[i][j] = (f32x4){0.f, 0.f, 0.f, 0.f};

    for (int ks = 0; ks < 8; ++ks) {
        const int k0 = ks * 32 + lq * 8;
        bf16x8 a[4];
#pragma unroll
        for (int mf = 0; mf < 4; ++mf) {
            const float* xp = x + (long)(r0 + mf * 16 + l15) * 256 + k0;
            float4 u = *(const float4*)xp;
            float4 v = *(const float4*)(xp + 4);
            bf16x8 t;
            t[0] = f2bf(u.x); t[1] = f2bf(u.y); t[2] = f2bf(u.z); t[3] = f2bf(u.w);
            t[4] = f2bf(v.x); t[5] = f2bf(v.y); t[6] = f2bf(v.z); t[7] = f2bf(v.w);
            a[mf] = t;
        }
#pragma unroll
        for (int nf = 0; nf < 6; ++nf) {
            const int n = wave * 96 + nf * 16 + l15;
            bf16x8 b = *(const bf16x8*)(wt + n * 256 + k0);
#pragma unroll
            for (int mf = 0; mf < 4; ++mf) acc[mf][nf] = MFMA(a[mf], b, acc[mf][nf]);
        }
    }
#pragma unroll
    for (int nf = 0; nf < 6; ++nf) {
        const int col = wave * 96 + nf * 16 + l15;
        const float bias = (col < 128) ? bk[col] : ((col < 256) ? bv[col - 128] : bq[col - 256]);
#pragma unroll
        for (int mf = 0; mf < 4; ++mf) {
#pragma unroll
            for (int rr = 0; rr < 4; ++rr) {
                float v = acc[mf][nf][rr] + bias;
                v = (v > 0.f) ? v : (__expf(v) - 1.f);
                kvq[(long)(r0 + mf * 16 + lq * 4 + rr) * 384 + col] = f2bf(v);
            }
        }
    }
}

// ---------------------------------------------------------------------------
// Generic "A^T @ B" partial GEMM, reducing over rows of A and B.
//   part[rs][m][c] += sum_{r in split rs} A[r][mt*128+m] * B[r][c]
// A: [R x lda] (cols -> out rows), B: [R x ldb] (first COLS cols used).
// Block: 128 out-rows x COLS, 4 waves (wave owns 32 out-rows).
template <int COLS, int AF32, int BF32>
__global__ __launch_bounds__(256) void pgemm_kernel(
    const void* __restrict__ Agv, const void* __restrict__ Bgv,
    const int lda, const int ldb, const int rchunks, const int rstride,
    float* __restrict__ part)
{
    __shared__ __align__(16) short As[128][72];
    __shared__ __align__(16) short Bs[COLS][72];
    const int tid = threadIdx.x;
    const int wave = tid >> 6, lane = tid & 63;
    const int l15 = lane & 15, lq = lane >> 4;
    const int mt = blockIdx.x, rs = blockIdx.y;
    const long b0 = (long)rs * rstride;
    constexpr int NCF = COLS / 16;
    constexpr int CPT = COLS / 8;

    f32x4 acc[2][NCF];
    for (int s = 0; s < 2; ++s)
        for (int c = 0; c < NCF; ++c) acc[s][c] = (f32x4){0.f, 0.f, 0.f, 0.f};

    const int sr  = (tid & 31) * 2;         // staged row pair
    const int am0 = (tid >> 5) * 16;        // A col group (16 cols)
    const int bc0 = (tid >> 5) * CPT;       // B col group

    for (int ch = 0; ch < rchunks; ++ch) {
        const long rb = b0 + (long)ch * 64;
        if constexpr (AF32) {
            const float* p0 = (const float*)Agv + (rb + sr) * lda + mt * 128 + am0;
            const float* p1 = p0 + lda;
#pragma unroll
            for (int j = 0; j < 16; ++j)
                *(uint32_t*)&As[am0 + j][sr] = pack2(p0[j], p1[j]);
        } else {
            const short* p0 = (const short*)Agv + (rb + sr) * lda + mt * 128 + am0;
            const short* p1 = p0 + lda;
#pragma unroll
            for (int g = 0; g < 2; ++g) {
                bf16x8 u = *(const bf16x8*)(p0 + g * 8);
                bf16x8 v = *(const bf16x8*)(p1 + g * 8);
#pragma unroll
                for (int j = 0; j < 8; ++j)
                    *(uint32_t*)&As[am0 + g * 8 + j][sr] =
                        (uint32_t)(uint16_t)u[j] | ((uint32_t)(uint16_t)v[j] << 16);
            }
        }
        if constexpr (BF32) {
            const float* p0 = (const float*)Bgv + (rb + sr) * ldb + bc0;
            const float* p1 = p0 + ldb;
#pragma unroll
            for (int j = 0; j < CPT; ++j)
                *(uint32_t*)&Bs[bc0 + j][sr] = pack2(p0[j], p1[j]);
        } else {
            const short* p0 = (const short*)Bgv + (rb + sr) * ldb + bc0;
            const short* p1 = p0 + ldb;
#pragma unroll
            for (int g = 0; g < CPT / 8; ++g) {
                bf16x8 u = *(const bf16x8*)(p0 + g * 8);
                bf16x8 v = *(const bf16x8*)(p1 + g * 8);
#pragma unroll
                for (int j = 0; j < 8; ++j)
                    *(uint32_t*)&Bs[bc0 + g * 8 + j][sr] =
                        (uint32_t)(uint16_t)u[j] | ((uint32_t)(uint16_t)v[j] << 16);
            }
        }
        __syncthreads();
#pragma unroll
        for (int ks = 0; ks < 2; ++ks) {
            bf16x8 a0 = *(const bf16x8*)&As[wave * 32 + l15][ks * 32 + lq * 8];
            bf16x8 a1 = *(const bf16x8*)&As[wave * 32 + 16 + l15][ks * 32 + lq * 8];
#pragma unroll
            for (int cf = 0; cf < NCF; ++cf) {
                bf16x8 b = *(const bf16x8*)&Bs[cf * 16 + l15][ks * 32 + lq * 8];
                acc[0][cf] = MFMA(a0, b, acc[0][cf]);
                acc[1][cf] = MFMA(a1, b, acc[1][cf]);
            }
        }
        __syncthreads();
    }
    float* pp = part + (long)rs * 1024 * COLS;
#pragma unroll
    for (int s = 0; s < 2; ++s)
#pragma unroll
        for (int cf = 0; cf < NCF; ++cf)
#pragma unroll
            for (int rr = 0; rr < 4; ++rr) {
                const int m = mt * 128 + wave * 32 + s * 16 + lq * 4 + rr;
                pp[(long)m * COLS + cf * 16 + l15] = acc[s][cf][rr];
            }
}

// ---------------------------------------------------------------------------
// Sum 8 partial slices [1024x128] -> bf16 P^T table [n][k].
__global__ void finp_kernel(const float* __restrict__ part, short* __restrict__ pt) {
    const int i = blockIdx.x * 256 + threadIdx.x;  // 131072 total
    float s = 0.f;
#pragma unroll
    for (int k = 0; k < 8; ++k) s += part[k * 131072 + i];
    pt[i] = f2bf(s);
}

// ---------------------------------------------------------------------------
// Sum 16 partial slices [1024x256], scale 1/B, add old memories.
// Outputs: km_new fp32 [1024][128], vmt bf16 transposed [128][1024].
__global__ void finmem_kernel(const float* __restrict__ part,
                              const float* __restrict__ km, const float* __restrict__ vm,
                              float* __restrict__ km_new, short* __restrict__ vmt) {
    const int m = blockIdx.x;      // 0..1023
    const int c = threadIdx.x;     // 0..255
    float s = 0.f;
#pragma unroll
    for (int k = 0; k < 16; ++k) s += part[(long)k * 262144 + m * 256 + c];
    s *= (1.0f / 32768.0f);
    if (c < 128) {
        km_new[m * 128 + c] = km[m * 128 + c] + s;
    } else {
        const int v = c - 128;
        vmt[v * 1024 + m] = f2bf(vm[m * 128 + v] + s);
    }
}

// ---------------------------------------------------------------------------
// write_w = softmax(key_vec @ P1 + bwr), output bf16 [B][1024].
// Block: 32 rows; GEMM phase: wave owns 16 n-tiles; softmax: wave owns 8 rows.
__global__ __launch_bounds__(256) void wsm_kernel(
    const short* __restrict__ kvq, const short* __restrict__ pt,
    const float* __restrict__ bias, short* __restrict__ wout)
{
    __shared__ __align__(16) short L[32][1048];
    const int tid = threadIdx.x;
    const int wave = tid >> 6, lane = tid & 63;
    const int l15 = lane & 15, lq = lane >> 4;
    const int r0 = blockIdx.x * 32;

    bf16x8 a[2][4];
#pragma unroll
    for (int mf = 0; mf < 2; ++mf)
#pragma unroll
        for (int ks = 0; ks < 4; ++ks)
            a[mf][ks] = *(const bf16x8*)(kvq + (long)(r0 + mf * 16 + l15) * 384 + ks * 32 + lq * 8);

    for (int nt = 0; nt < 16; ++nt) {
        const int ncol = (wave * 16 + nt) * 16 + l15;
        f32x4 c0 = {0.f, 0.f, 0.f, 0.f}, c1 = {0.f, 0.f, 0.f, 0.f};
#pragma unroll
        for (int ks = 0; ks < 4; ++ks) {
            bf16x8 b = *(const bf16x8*)(pt + ncol * 128 + ks * 32 + lq * 8);
            c0 = MFMA(a[0][ks], b, c0);
            c1 = MFMA(a[1][ks], b, c1);
        }
#pragma unroll
        for (int rr = 0; rr < 4; ++rr) {
            L[lq * 4 + rr][ncol] = f2bf(c0[rr]);
            L[16 + lq * 4 + rr][ncol] = f2bf(c1[rr]);
        }
    }
    __syncthreads();

    float breg[16];
#pragma unroll
    for (int k = 0; k < 16; ++k) breg[k] = bias[lane + 64 * k];
    for (int rw = 0; rw < 8; ++rw) {
        const int row = wave * 8 + rw;
        float p[16];
        float mx = -3.0e38f;
#pragma unroll
        for (int k = 0; k < 16; ++k) {
            float v = bf2f(L[row][lane + 64 * k]) + breg[k];
            p[k] = v;
            mx = fmaxf(mx, v);
        }
#pragma unroll
        for (int off = 32; off; off >>= 1) mx = fmaxf(mx, __shfl_xor(mx, off));
        float sum = 0.f;
#pragma unroll
        for (int k = 0; k < 16; ++k) { p[k] = __expf(p[k] - mx); sum += p[k]; }
#pragma unroll
        for (int off = 32; off; off >>= 1) sum += __shfl_xor(sum, off);
        const float inv = 1.f / sum;
        short* wp = wout + (long)(r0 + row) * 1024 + lane;
#pragma unroll
        for (int k = 0; k < 16; ++k) wp[64 * k] = f2bf(p[k] * inv);
    }
}

// ---------------------------------------------------------------------------
// Fused read path: logits = qry @ P2 + brd; softmax; out = read_w @ val_mem_new.
__global__ __launch_bounds__(256) void rsm_kernel(
    const short* __restrict__ kvq, const short* __restrict__ pt,
    const float* __restrict__ bias, const short* __restrict__ vmt,
    float* __restrict__ out)
{
    __shared__ __align__(16) short L[32][1048];
    __shared__ float invs[32];
    const int tid = threadIdx.x;
    const int wave = tid >> 6, lane = tid & 63;
    const int l15 = lane & 15, lq = lane >> 4;
    const int r0 = blockIdx.x * 32;

    bf16x8 a[2][4];
#pragma unroll
    for (int mf = 0; mf < 2; ++mf)
#pragma unroll
        for (int ks = 0; ks < 4; ++ks)
            a[mf][ks] = *(const bf16x8*)(kvq + (long)(r0 + mf * 16 + l15) * 384 + 256 + ks * 32 + lq * 8);

    for (int nt = 0; nt < 16; ++nt) {
        const int ncol = (wave * 16 + nt) * 16 + l15;
        f32x4 c0 = {0.f, 0.f, 0.f, 0.f}, c1 = {0.f, 0.f, 0.f, 0.f};
#pragma unroll
        for (int ks = 0; ks < 4; ++ks) {
            bf16x8 b = *(const bf16x8*)(pt + ncol * 128 + ks * 32 + lq * 8);
            c0 = MFMA(a[0][ks], b, c0);
            c1 = MFMA(a[1][ks], b, c1);
        }
#pragma unroll
        for (int rr = 0; rr < 4; ++rr) {
            L[lq * 4 + rr][ncol] = f2bf(c0[rr]);
            L[16 + lq * 4 + rr][ncol] = f2bf(c1[rr]);
        }
    }
    __syncthreads();

    float breg[16];
#pragma unroll
    for (int k = 0; k < 16; ++k) breg[k] = bias[lane + 64 * k];
    for (int rw = 0; rw < 8; ++rw) {
        const int row = wave * 8 + rw;
        float p[16];
        float mx = -3.0e38f;
#pragma unroll
        for (int k = 0; k < 16; ++k) {
            float v = bf2f(L[row][lane + 64 * k]) + breg[k];
            p[k] = v;
            mx = fmaxf(mx, v);
        }
#pragma unroll
        for (int off = 32; off; off >>= 1) mx = fmaxf(mx, __shfl_xor(mx, off));
        float sum = 0.f;
#pragma unroll
        for (int k = 0; k < 16; ++k) { p[k] = __expf(p[k] - mx); sum += p[k]; }
#pragma unroll
        for (int off = 32; off; off >>= 1) sum += __shfl_xor(sum, off);
        // write unnormalized p back (same lane-owned slots), scale at the end
#pragma unroll
        for (int k = 0; k < 16; ++k) L[row][lane + 64 * k] = f2bf(p[k]);
        if (lane == 0) invs[row] = 1.f / sum;
    }
    __syncthreads();

    // PV: out[32 x 128] = p @ vmt^T; wave owns 2 col-tiles (32 cols).
    f32x4 acc[2][2];
    for (int i = 0; i < 2; ++i)
        for (int j = 0; j < 2; ++j) acc[i][j] = (f32x4){0.f, 0.f, 0.f, 0.f};
    for (int ks = 0; ks < 32; ++ks) {
        bf16x8 a0 = *(const bf16x8*)&L[l15][ks * 32 + lq * 8];
        bf16x8 a1 = *(const bf16x8*)&L[16 + l15][ks * 32 + lq * 8];
#pragma unroll
        for (int nf = 0; nf < 2; ++nf) {
            const int n = (wave * 2 + nf) * 16 + l15;
            bf16x8 b = *(const bf16x8*)(vmt + n * 1024 + ks * 32 + lq * 8);
            acc[0][nf] = MFMA(a0, b, acc[0][nf]);
            acc[1][nf] = MFMA(a1, b, acc[1][nf]);
        }
    }
#pragma unroll
    for (int mf = 0; mf < 2; ++mf)
#pragma unroll
        for (int nf = 0; nf < 2; ++nf)
#pragma unroll
            for (int rr = 0; rr < 4; ++rr) {
                const int row = mf * 16 + lq * 4 + rr;
                const int col = (wave * 2 + nf) * 16 + l15;
                out[(long)(r0 + row) * 128 + col] = acc[mf][nf][rr] * invs[row];
            }
}

// ---------------------------------------------------------------------------
extern "C" void kernel_launch(void* const* d_in, const int* in_sizes, int n_in,
                              void* d_out, int out_size, void* d_ws, size_t ws_size,
                              hipStream_t stream)
{
    const float* x   = (const float*)d_in[0];
    const float* Wk  = (const float*)d_in[1];
    const float* bk  = (const float*)d_in[2];
    const float* Wv  = (const float*)d_in[3];
    const float* bv  = (const float*)d_in[4];
    const float* Wq  = (const float*)d_in[5];
    const float* bq  = (const float*)d_in[6];
    const float* Wwr = (const float*)d_in[7];
    const float* bwr = (const float*)d_in[8];
    const float* Wrd = (const float*)d_in[9];
    const float* brd = (const float*)d_in[10];
    const float* km  = (const float*)d_in[11];
    const float* vm  = (const float*)d_in[12];
    float* out = (float*)d_out;

    char* ws = (char*)d_ws;
    short* kvq  = (short*)(ws + 0);           // 32768*384*2  = 25165824
    short* w    = (short*)(ws + 25165824);    // 32768*1024*2 = 67108864
    float* part = (float*)(ws + 92274688);    // 16*1024*256*4 = 16777216 (reused)
    short* p1t  = (short*)(ws + 109051904);   // 262144
    short* p2t  = (short*)(ws + 109314048);   // 262144
    float* kmn  = (float*)(ws + 109576192);   // 524288
    short* vmt  = (short*)(ws + 110100480);   // 262144
    short* wt   = (short*)(ws + 110362624);   // 196608  -> total 110559232
    if (ws_size < 110559232u) return;         // insufficient scratch: fail cleanly

    kw_kernel<<<384, 256, 0, stream>>>(Wk, Wv, Wq, wt);
    proj_kernel<<<512, 256, 0, stream>>>(x, wt, bk, bv, bq, kvq);
    // P1 = key_memory^T @ Wwr  (stored transposed [n][k])
    pgemm_kernel<128, 1, 1><<<dim3(8, 8), 256, 0, stream>>>(Wwr, km, 1024, 128, 2, 128, part);
    finp_kernel<<<512, 256, 0, stream>>>(part, p1t);
    wsm_kernel<<<1024, 256, 0, stream>>>(kvq, p1t, bwr, w);
    // einsum updates: [1024 x 256] = write_w^T @ [key|val]
    pgemm_kernel<256, 0, 0><<<dim3(8, 16), 256, 0, stream>>>(w, kvq, 1024, 384, 32, 2048, part);
    finmem_kernel<<<1024, 256, 0, stream>>>(part, km, vm, kmn, vmt);
    // P2 = key_mem_new^T @ Wrd
    pgemm_kernel<128, 1, 1><<<dim3(8, 8), 256, 0, stream>>>(Wrd, kmn, 1024, 128, 2, 128, part);
    finp_kernel<<<512, 256, 0, stream>>>(part, p2t);
    rsm_kernel<<<1024, 256, 0, stream>>>(kvq, p2t, brd, vmt, out);
}

// Round 2
// 234.534 us; speedup vs baseline: 1.2508x; 1.2508x over previous
//
#include <hip/hip_runtime.h>
#include <stdint.h>

// MemoryAugmentedLayer: B=32768, D=256, M=1024, K=V=128.
// Restructured: logits = kvec @ (KM^T @ W) instead of (kvec @ KM^T) @ W.
// All big GEMMs in bf16 MFMA 16x16x32, fp32 accumulate.

typedef short bf16x8 __attribute__((ext_vector_type(8)));
typedef short s16x4  __attribute__((ext_vector_type(4)));
typedef float f32x4  __attribute__((ext_vector_type(4)));

#define MFMA(a, b, c) __builtin_amdgcn_mfma_f32_16x16x32_bf16((a), (b), (c), 0, 0, 0)

__device__ __forceinline__ short f2bf(float f) {
    union { float f; uint32_t u; } v; v.f = f;
    uint32_t r = (v.u + 0x7FFFu + ((v.u >> 16) & 1u)) >> 16;
    return (short)r;
}
__device__ __forceinline__ float bf2f(short h) {
    union { uint32_t u; float f; } v; v.u = ((uint32_t)(uint16_t)h) << 16;
    return v.f;
}
__device__ __forceinline__ uint32_t pack2(float a, float b) {
    return (uint32_t)(uint16_t)f2bf(a) | ((uint32_t)(uint16_t)f2bf(b) << 16);
}
__device__ __forceinline__ unsigned lds_addr(const void* p) {
    return (unsigned)(uintptr_t)(__attribute__((address_space(3))) const void*)p;
}
// transpose-read: lane reads 4 bf16 at vaddr + j*32B  (j = 0..3)
__device__ __forceinline__ s16x4 trrd(unsigned a) {
    s16x4 d;
    asm volatile("ds_read_b64_tr_b16 %0, %1" : "=v"(d) : "v"(a));
    return d;
}
__device__ __forceinline__ bf16x8 cat8(s16x4 lo, s16x4 hi) {
    bf16x8 r;
    r[0] = lo[0]; r[1] = lo[1]; r[2] = lo[2]; r[3] = lo[3];
    r[4] = hi[0]; r[5] = hi[1]; r[6] = hi[2]; r[7] = hi[3];
    return r;
}
#define GLDS(g, l) __builtin_amdgcn_global_load_lds(                          \
    (const __attribute__((address_space(1))) void*)(g),                       \
    (__attribute__((address_space(3))) void*)(l), 16, 0, 0)

// ---------------------------------------------------------------------------
// Wt[c][d] = bf16(W{k,v,q}[d][c&127]),  c in [0,384), d in [0,256)
__global__ void kw_kernel(const float* __restrict__ Wk, const float* __restrict__ Wv,
                          const float* __restrict__ Wq, short* __restrict__ wt) {
    const int c = blockIdx.x;       // 0..383
    const int d = threadIdx.x;      // 0..255
    const float* W = (c < 128) ? Wk : ((c < 256) ? Wv : Wq);
    wt[c * 256 + d] = f2bf(W[d * 128 + (c & 127)]);
}

// ---------------------------------------------------------------------------
// kvq[b][0:384] = elu(x @ [Wk|Wv|Wq] + [bk|bv|bq]) in bf16.
__global__ __launch_bounds__(256) void proj_kernel(
    const float* __restrict__ x, const short* __restrict__ wt,
    const float* __restrict__ bk, const float* __restrict__ bv,
    const float* __restrict__ bq, short* __restrict__ kvq)
{
    const int tid = threadIdx.x;
    const int wave = tid >> 6, lane = tid & 63;
    const int l15 = lane & 15, lq = lane >> 4;
    const int r0 = blockIdx.x * 64;

    f32x4 acc[4][6];
    for (int i = 0; i < 4; ++i)
        for (int j = 0; j < 6; ++j) acc[i][j] = (f32x4){0.f, 0.f, 0.f, 0.f};

    for (int ks = 0; ks < 8; ++ks) {
        const int k0 = ks * 32 + lq * 8;
        bf16x8 a[4];
#pragma unroll
        for (int mf = 0; mf < 4; ++mf) {
            const float* xp = x + (long)(r0 + mf * 16 + l15) * 256 + k0;
            float4 u = *(const float4*)xp;
            float4 v = *(const float4*)(xp + 4);
            bf16x8 t;
            t[0] = f2bf(u.x); t[1] = f2bf(u.y); t[2] = f2bf(u.z); t[3] = f2bf(u.w);
            t[4] = f2bf(v.x); t[5] = f2bf(v.y); t[6] = f2bf(v.z); t[7] = f2bf(v.w);
            a[mf] = t;
        }
#pragma unroll
        for (int nf = 0; nf < 6; ++nf) {
            const int n = wave * 96 + nf * 16 + l15;
            bf16x8 b = *(const bf16x8*)(wt + n * 256 + k0);
#pragma unroll
            for (int mf = 0; mf < 4; ++mf) acc[mf][nf] = MFMA(a[mf], b, acc[mf][nf]);
        }
    }
#pragma unroll
    for (int nf = 0; nf < 6; ++nf) {
        const int col = wave * 96 + nf * 16 + l15;
        const float bias = (col < 128) ? bk[col] : ((col < 256) ? bv[col - 128] : bq[col - 256]);
#pragma unroll
        for (int mf = 0; mf < 4; ++mf) {
#pragma unroll
            for (int rr = 0; rr < 4; ++rr) {
                float v = acc[mf][nf][rr] + bias;
                v = (v > 0.f) ? v : (__expf(v) - 1.f);
                kvq[(long)(r0 + mf * 16 + lq * 4 + rr) * 384 + col] = f2bf(v);
            }
        }
    }
}

// ---------------------------------------------------------------------------
// Small fp32 "A^T @ B" partial GEMM for P1/P2 (K=1024 reduction, out 1024x128).
template <int COLS, int AF32, int BF32>
__global__ __launch_bounds__(256) void pgemm_kernel(
    const void* __restrict__ Agv, const void* __restrict__ Bgv,
    const int lda, const int ldb, const int rchunks, const int rstride,
    float* __restrict__ part)
{
    __shared__ __align__(16) short As[128][72];
    __shared__ __align__(16) short Bs[COLS][72];
    const int tid = threadIdx.x;
    const int wave = tid >> 6, lane = tid & 63;
    const int l15 = lane & 15, lq = lane >> 4;
    const int mt = blockIdx.x, rs = blockIdx.y;
    const long b0 = (long)rs * rstride;
    constexpr int NCF = COLS / 16;
    constexpr int CPT = COLS / 8;

    f32x4 acc[2][NCF];
    for (int s = 0; s < 2; ++s)
        for (int c = 0; c < NCF; ++c) acc[s][c] = (f32x4){0.f, 0.f, 0.f, 0.f};

    const int sr  = (tid & 31) * 2;
    const int am0 = (tid >> 5) * 16;
    const int bc0 = (tid >> 5) * CPT;

    for (int ch = 0; ch < rchunks; ++ch) {
        const long rb = b0 + (long)ch * 64;
        {
            const float* p0 = (const float*)Agv + (rb + sr) * lda + mt * 128 + am0;
            const float* p1 = p0 + lda;
#pragma unroll
            for (int j = 0; j < 16; ++j)
                *(uint32_t*)&As[am0 + j][sr] = pack2(p0[j], p1[j]);
        }
        {
            const float* p0 = (const float*)Bgv + (rb + sr) * ldb + bc0;
            const float* p1 = p0 + ldb;
#pragma unroll
            for (int j = 0; j < CPT; ++j)
                *(uint32_t*)&Bs[bc0 + j][sr] = pack2(p0[j], p1[j]);
        }
        __syncthreads();
#pragma unroll
        for (int ks = 0; ks < 2; ++ks) {
            bf16x8 a0 = *(const bf16x8*)&As[wave * 32 + l15][ks * 32 + lq * 8];
            bf16x8 a1 = *(const bf16x8*)&As[wave * 32 + 16 + l15][ks * 32 + lq * 8];
#pragma unroll
            for (int cf = 0; cf < NCF; ++cf) {
                bf16x8 b = *(const bf16x8*)&Bs[cf * 16 + l15][ks * 32 + lq * 8];
                acc[0][cf] = MFMA(a0, b, acc[0][cf]);
                acc[1][cf] = MFMA(a1, b, acc[1][cf]);
            }
        }
        __syncthreads();
    }
    float* pp = part + (long)rs * 1024 * COLS;
#pragma unroll
    for (int s = 0; s < 2; ++s)
#pragma unroll
        for (int cf = 0; cf < NCF; ++cf)
#pragma unroll
            for (int rr = 0; rr < 4; ++rr) {
                const int m = mt * 128 + wave * 32 + s * 16 + lq * 4 + rr;
                pp[(long)m * COLS + cf * 16 + l15] = acc[s][cf][rr];
            }
}

// ---------------------------------------------------------------------------
// Sum 8 partial slices [1024x128] -> bf16 P^T table [n][k].
__global__ void finp_kernel(const float* __restrict__ part, short* __restrict__ pt) {
    const int i = blockIdx.x * 256 + threadIdx.x;
    float s = 0.f;
#pragma unroll
    for (int k = 0; k < 8; ++k) s += part[k * 131072 + i];
    pt[i] = f2bf(s);
}

// ---------------------------------------------------------------------------
// Einsum GEMM: part[ks][m][c] = sum_{k in split ks} w[k][m] * kvq[k][c]
// grid (16, 32): blockIdx.x = tile (mt = x>>1 of 8, ct = x&1 of 2), y = K-split.
// Per block: out 128x128, K = 1024 in 16 chunks of 64.
// LDS tiles stored subtiled [mb][kb][4][16] (subtile idx = mb*16+kb), written
// LINEARLY by global_load_lds with pre-swizzled per-lane source addresses,
// read by ds_read_b64_tr_b16. K-permutation identical for A and B -> exact.
__global__ __launch_bounds__(256) void eins_kernel(
    const short* __restrict__ w,    // [32768][1024] bf16 (write_w)
    const short* __restrict__ kvq,  // [32768][384]  bf16 (key|val|qry)
    short* __restrict__ part)       // [32][1024][256] bf16 partials
{
    __shared__ __align__(16) short As[8192];  // 16 KB
    __shared__ __align__(16) short Bs[8192];  // 16 KB
    const int tid = threadIdx.x;
    const int wave = tid >> 6, lane = tid & 63;
    const int l15 = lane & 15, lq = lane >> 4;
    const int mt = blockIdx.x >> 1, ct = blockIdx.x & 1;
    const int ks = blockIdx.y;
    const long k0_blk = (long)ks * 1024;

    // staging descriptors: issue t covers LDS elems [t*512, t*512+512)
    // lane i: s = t*8+(i>>3); k_local = (s&15)*4+((i&7)>>1); m = (s>>4)*16+(i&1)*8
    int aoff[4], boff[4];
    const short* ldsA[4];
    const short* ldsB[4];
#pragma unroll
    for (int q = 0; q < 4; ++q) {
        const int t = wave + q * 4;
        const int s = t * 8 + (lane >> 3);
        const int kl = (s & 15) * 4 + ((lane & 7) >> 1);
        const int m  = (s >> 4) * 16 + (lane & 1) * 8;
        aoff[q] = kl * 1024 + mt * 128 + m;
        boff[q] = kl * 384  + ct * 128 + m;
        ldsA[q] = &As[t * 512];
        ldsB[q] = &Bs[t * 512];
    }

    f32x4 acc[4][4];
    for (int i = 0; i < 4; ++i)
        for (int j = 0; j < 4; ++j) acc[i][j] = (f32x4){0.f, 0.f, 0.f, 0.f};

    const int wr = wave >> 1, wc = wave & 1;
    const unsigned trb = lds_addr(As) + 2u * (l15 + lq * 64);
    const unsigned trbB = lds_addr(Bs) + 2u * (l15 + lq * 64);

    for (int ch = 0; ch < 16; ++ch) {
        const short* wa = w   + (k0_blk + ch * 64) * 1024;
        const short* kb = kvq + (k0_blk + ch * 64) * 384;
#pragma unroll
        for (int q = 0; q < 4; ++q) {
            GLDS(wa + aoff[q], ldsA[q]);
            GLDS(kb + boff[q], ldsB[q]);
        }
        __syncthreads();   // drains vmcnt before barrier
#pragma unroll
        for (int kst = 0; kst < 2; ++kst) {
            s16x4 ah[4][2], bh[4][2];
#pragma unroll
            for (int f = 0; f < 4; ++f) {
#pragma unroll
                for (int h = 0; h < 2; ++h) {
                    ah[f][h] = trrd(trb  + 128u * ((wr * 4 + f) * 16 + kst * 8 + h * 4));
                    bh[f][h] = trrd(trbB + 128u * ((wc * 4 + f) * 16 + kst * 8 + h * 4));
                }
            }
            asm volatile("s_waitcnt lgkmcnt(0)" ::: "memory");
            __builtin_amdgcn_sched_barrier(0);
#pragma unroll
            for (int mf = 0; mf < 4; ++mf) {
                bf16x8 a = cat8(ah[mf][0], ah[mf][1]);
#pragma unroll
                for (int cf = 0; cf < 4; ++cf)
                    acc[mf][cf] = MFMA(a, cat8(bh[cf][0], bh[cf][1]), acc[mf][cf]);
            }
        }
        __syncthreads();
    }

    short* pp = part + ((long)ks * 1024 + mt * 128) * 256 + ct * 128;
#pragma unroll
    for (int mf = 0; mf < 4; ++mf)
#pragma unroll
        for (int cf = 0; cf < 4; ++cf)
#pragma unroll
            for (int rr = 0; rr < 4; ++rr) {
                const int m = wr * 64 + mf * 16 + lq * 4 + rr;
                const int c = wc * 64 + cf * 16 + l15;
                pp[(long)m * 256 + c] = f2bf(acc[mf][cf][rr]);
            }
}

// ---------------------------------------------------------------------------
// Sum 32 bf16 partial slices [1024x256], scale 1/B, add old memories.
__global__ void finmem_kernel(const short* __restrict__ part,
                              const float* __restrict__ km, const float* __restrict__ vm,
                              float* __restrict__ km_new, short* __restrict__ vmt) {
    const int m = blockIdx.x;      // 0..1023
    const int c = threadIdx.x;     // 0..255
    float s = 0.f;
#pragma unroll
    for (int k = 0; k < 32; ++k) s += bf2f(part[k * 262144 + m * 256 + c]);
    s *= (1.0f / 32768.0f);
    if (c < 128) {
        km_new[m * 128 + c] = km[m * 128 + c] + s;
    } else {
        const int v = c - 128;
        vmt[v * 1024 + m] = f2bf(vm[m * 128 + v] + s);
    }
}

// ---------------------------------------------------------------------------
// write_w = softmax(key_vec @ P1 + bwr), output bf16 [B][1024].
__global__ __launch_bounds__(256) void wsm_kernel(
    const short* __restrict__ kvq, const short* __restrict__ pt,
    const float* __restrict__ bias, short* __restrict__ wout)
{
    __shared__ __align__(16) short L[32][1048];
    const int tid = threadIdx.x;
    const int wave = tid >> 6, lane = tid & 63;
    const int l15 = lane & 15, lq = lane >> 4;
    const int r0 = blockIdx.x * 32;

    bf16x8 a[2][4];
#pragma unroll
    for (int mf = 0; mf < 2; ++mf)
#pragma unroll
        for (int ks = 0; ks < 4; ++ks)
            a[mf][ks] = *(const bf16x8*)(kvq + (long)(r0 + mf * 16 + l15) * 384 + ks * 32 + lq * 8);

    for (int nt = 0; nt < 16; ++nt) {
        const int ncol = (wave * 16 + nt) * 16 + l15;
        f32x4 c0 = {0.f, 0.f, 0.f, 0.f}, c1 = {0.f, 0.f, 0.f, 0.f};
#pragma unroll
        for (int ks = 0; ks < 4; ++ks) {
            bf16x8 b = *(const bf16x8*)(pt + ncol * 128 + ks * 32 + lq * 8);
            c0 = MFMA(a[0][ks], b, c0);
            c1 = MFMA(a[1][ks], b, c1);
        }
#pragma unroll
        for (int rr = 0; rr < 4; ++rr) {
            L[lq * 4 + rr][ncol] = f2bf(c0[rr]);
            L[16 + lq * 4 + rr][ncol] = f2bf(c1[rr]);
        }
    }
    __syncthreads();

    float breg[16];
#pragma unroll
    for (int k = 0; k < 16; ++k) breg[k] = bias[lane + 64 * k];
    for (int rw = 0; rw < 8; ++rw) {
        const int row = wave * 8 + rw;
        float p[16];
        float mx = -3.0e38f;
#pragma unroll
        for (int k = 0; k < 16; ++k) {
            float v = bf2f(L[row][lane + 64 * k]) + breg[k];
            p[k] = v;
            mx = fmaxf(mx, v);
        }
#pragma unroll
        for (int off = 32; off; off >>= 1) mx = fmaxf(mx, __shfl_xor(mx, off));
        float sum = 0.f;
#pragma unroll
        for (int k = 0; k < 16; ++k) { p[k] = __expf(p[k] - mx); sum += p[k]; }
#pragma unroll
        for (int off = 32; off; off >>= 1) sum += __shfl_xor(sum, off);
        const float inv = 1.f / sum;
        short* wp = wout + (long)(r0 + row) * 1024 + lane;
#pragma unroll
        for (int k = 0; k < 16; ++k) wp[64 * k] = f2bf(p[k] * inv);
    }
}

// ---------------------------------------------------------------------------
// Fused read path: logits = qry @ P2 + brd; softmax; out = read_w @ val_mem_new.
__global__ __launch_bounds__(256) void rsm_kernel(
    const short* __restrict__ kvq, const short* __restrict__ pt,
    const float* __restrict__ bias, const short* __restrict__ vmt,
    float* __restrict__ out)
{
    __shared__ __align__(16) short L[32][1048];
    __shared__ float invs[32];
    const int tid = threadIdx.x;
    const int wave = tid >> 6, lane = tid & 63;
    const int l15 = lane & 15, lq = lane >> 4;
    const int r0 = blockIdx.x * 32;

    bf16x8 a[2][4];
#pragma unroll
    for (int mf = 0; mf < 2; ++mf)
#pragma unroll
        for (int ks = 0; ks < 4; ++ks)
            a[mf][ks] = *(const bf16x8*)(kvq + (long)(r0 + mf * 16 + l15) * 384 + 256 + ks * 32 + lq * 8);

    for (int nt = 0; nt < 16; ++nt) {
        const int ncol = (wave * 16 + nt) * 16 + l15;
        f32x4 c0 = {0.f, 0.f, 0.f, 0.f}, c1 = {0.f, 0.f, 0.f, 0.f};
#pragma unroll
        for (int ks = 0; ks < 4; ++ks) {
            bf16x8 b = *(const bf16x8*)(pt + ncol * 128 + ks * 32 + lq * 8);
            c0 = MFMA(a[0][ks], b, c0);
            c1 = MFMA(a[1][ks], b, c1);
        }
#pragma unroll
        for (int rr = 0; rr < 4; ++rr) {
            L[lq * 4 + rr][ncol] = f2bf(c0[rr]);
            L[16 + lq * 4 + rr][ncol] = f2bf(c1[rr]);
        }
    }
    __syncthreads();

    float breg[16];
#pragma unroll
    for (int k = 0; k < 16; ++k) breg[k] = bias[lane + 64 * k];
    for (int rw = 0; rw < 8; ++rw) {
        const int row = wave * 8 + rw;
        float p[16];
        float mx = -3.0e38f;
#pragma unroll
        for (int k = 0; k < 16; ++k) {
            float v = bf2f(L[row][lane + 64 * k]) + breg[k];
            p[k] = v;
            mx = fmaxf(mx, v);
        }
#pragma unroll
        for (int off = 32; off; off >>= 1) mx = fmaxf(mx, __shfl_xor(mx, off));
        float sum = 0.f;
#pragma unroll
        for (int k = 0; k < 16; ++k) { p[k] = __expf(p[k] - mx); sum += p[k]; }
#pragma unroll
        for (int off = 32; off; off >>= 1) sum += __shfl_xor(sum, off);
#pragma unroll
        for (int k = 0; k < 16; ++k) L[row][lane + 64 * k] = f2bf(p[k]);
        if (lane == 0) invs[row] = 1.f / sum;
    }
    __syncthreads();

    f32x4 acc[2][2];
    for (int i = 0; i < 2; ++i)
        for (int j = 0; j < 2; ++j) acc[i][j] = (f32x4){0.f, 0.f, 0.f, 0.f};
    for (int ks = 0; ks < 32; ++ks) {
        bf16x8 a0 = *(const bf16x8*)&L[l15][ks * 32 + lq * 8];
        bf16x8 a1 = *(const bf16x8*)&L[16 + l15][ks * 32 + lq * 8];
#pragma unroll
        for (int nf = 0; nf < 2; ++nf) {
            const int n = (wave * 2 + nf) * 16 + l15;
            bf16x8 b = *(const bf16x8*)(vmt + n * 1024 + ks * 32 + lq * 8);
            acc[0][nf] = MFMA(a0, b, acc[0][nf]);
            acc[1][nf] = MFMA(a1, b, acc[1][nf]);
        }
    }
#pragma unroll
    for (int mf = 0; mf < 2; ++mf)
#pragma unroll
        for (int nf = 0; nf < 2; ++nf)
#pragma unroll
            for (int rr = 0; rr < 4; ++rr) {
                const int row = mf * 16 + lq * 4 + rr;
                const int col = (wave * 2 + nf) * 16 + l15;
                out[(long)(r0 + row) * 128 + col] = acc[mf][nf][rr] * invs[row];
            }
}

// ---------------------------------------------------------------------------
extern "C" void kernel_launch(void* const* d_in, const int* in_sizes, int n_in,
                              void* d_out, int out_size, void* d_ws, size_t ws_size,
                              hipStream_t stream)
{
    const float* x   = (const float*)d_in[0];
    const float* Wk  = (const float*)d_in[1];
    const float* bk  = (const float*)d_in[2];
    const float* Wv  = (const float*)d_in[3];
    const float* bv  = (const float*)d_in[4];
    const float* Wq  = (const float*)d_in[5];
    const float* bq  = (const float*)d_in[6];
    const float* Wwr = (const float*)d_in[7];
    const float* bwr = (const float*)d_in[8];
    const float* Wrd = (const float*)d_in[9];
    const float* brd = (const float*)d_in[10];
    const float* km  = (const float*)d_in[11];
    const float* vm  = (const float*)d_in[12];
    float* out = (float*)d_out;

    char* ws = (char*)d_ws;
    short* kvq  = (short*)(ws + 0);           // 32768*384*2  = 25165824
    short* w    = (short*)(ws + 25165824);    // 32768*1024*2 = 67108864
    float* part = (float*)(ws + 92274688);    // 16 MB scratch (fp32 P-partials / bf16 einsum partials)
    short* p1t  = (short*)(ws + 109051904);   // 262144
    short* p2t  = (short*)(ws + 109314048);   // 262144
    float* kmn  = (float*)(ws + 109576192);   // 524288
    short* vmt  = (short*)(ws + 110100480);   // 262144
    short* wt   = (short*)(ws + 110362624);   // 196608  -> total 110559232
    if (ws_size < 110559232u) return;

    kw_kernel<<<384, 256, 0, stream>>>(Wk, Wv, Wq, wt);
    proj_kernel<<<512, 256, 0, stream>>>(x, wt, bk, bv, bq, kvq);
    // P1 = key_memory^T @ Wwr  (stored transposed [n][k])
    pgemm_kernel<128, 1, 1><<<dim3(8, 8), 256, 0, stream>>>(Wwr, km, 1024, 128, 2, 128, part);
    finp_kernel<<<512, 256, 0, stream>>>(part, p1t);
    wsm_kernel<<<1024, 256, 0, stream>>>(kvq, p1t, bwr, w);
    // einsum updates: [1024 x 256] = write_w^T @ [key|val]
    eins_kernel<<<dim3(16, 32), 256, 0, stream>>>(w, kvq, (short*)part);
    finmem_kernel<<<1024, 256, 0, stream>>>((const short*)part, km, vm, kmn, vmt);
    // P2 = key_mem_new^T @ Wrd
    pgemm_kernel<128, 1, 1><<<dim3(8, 8), 256, 0, stream>>>(Wrd, kmn, 1024, 128, 2, 128, part);
    finp_kernel<<<512, 256, 0, stream>>>(part, p2t);
    rsm_kernel<<<1024, 256, 0, stream>>>(kvq, p2t, brd, vmt, out);
}

// Round 3
// 226.656 us; speedup vs baseline: 1.2943x; 1.0348x over previous
//
#include <hip/hip_runtime.h>
#include <stdint.h>

// MemoryAugmentedLayer: B=32768, D=256, M=1024, K=V=128.
// Restructured: logits = kvec @ (KM^T @ W) instead of (kvec @ KM^T) @ W.
// All big GEMMs in bf16 MFMA 16x16x32, fp32 accumulate.

typedef short bf16x8 __attribute__((ext_vector_type(8)));
typedef short s16x4  __attribute__((ext_vector_type(4)));
typedef float f32x4  __attribute__((ext_vector_type(4)));

#define MFMA(a, b, c) __builtin_amdgcn_mfma_f32_16x16x32_bf16((a), (b), (c), 0, 0, 0)

__device__ __forceinline__ short f2bf(float f) {
    union { float f; uint32_t u; } v; v.f = f;
    uint32_t r = (v.u + 0x7FFFu + ((v.u >> 16) & 1u)) >> 16;
    return (short)r;
}
__device__ __forceinline__ float bf2f(short h) {
    union { uint32_t u; float f; } v; v.u = ((uint32_t)(uint16_t)h) << 16;
    return v.f;
}
__device__ __forceinline__ uint32_t pack2(float a, float b) {
    return (uint32_t)(uint16_t)f2bf(a) | ((uint32_t)(uint16_t)f2bf(b) << 16);
}
__device__ __forceinline__ unsigned lds_addr(const void* p) {
    return (unsigned)(uintptr_t)(__attribute__((address_space(3))) const void*)p;
}
__device__ __forceinline__ s16x4 trrd(unsigned a) {
    s16x4 d;
    asm volatile("ds_read_b64_tr_b16 %0, %1" : "=v"(d) : "v"(a));
    return d;
}
__device__ __forceinline__ bf16x8 cat8(s16x4 lo, s16x4 hi) {
    bf16x8 r;
    r[0] = lo[0]; r[1] = lo[1]; r[2] = lo[2]; r[3] = lo[3];
    r[4] = hi[0]; r[5] = hi[1]; r[6] = hi[2]; r[7] = hi[3];
    return r;
}
#define GLDS(g, l) __builtin_amdgcn_global_load_lds(                          \
    (const __attribute__((address_space(1))) void*)(g),                       \
    (__attribute__((address_space(3))) void*)(l), 16, 0, 0)

// ---------------------------------------------------------------------------
__global__ void kw_kernel(const float* __restrict__ Wk, const float* __restrict__ Wv,
                          const float* __restrict__ Wq, short* __restrict__ wt) {
    const int c = blockIdx.x;       // 0..383
    const int d = threadIdx.x;      // 0..255
    const float* W = (c < 128) ? Wk : ((c < 256) ? Wv : Wq);
    wt[c * 256 + d] = f2bf(W[d * 128 + (c & 127)]);
}

// ---------------------------------------------------------------------------
// kvq[b][0:384] = elu(x @ [Wk|Wv|Wq] + [bk|bv|bq]) in bf16.
__global__ __launch_bounds__(256) void proj_kernel(
    const float* __restrict__ x, const short* __restrict__ wt,
    const float* __restrict__ bk, const float* __restrict__ bv,
    const float* __restrict__ bq, short* __restrict__ kvq)
{
    const int tid = threadIdx.x;
    const int wave = tid >> 6, lane = tid & 63;
    const int l15 = lane & 15, lq = lane >> 4;
    const int r0 = blockIdx.x * 64;

    f32x4 acc[4][6];
    for (int i = 0; i < 4; ++i)
        for (int j = 0; j < 6; ++j) acc[i][j] = (f32x4){0.f, 0.f, 0.f, 0.f};

    for (int ks = 0; ks < 8; ++ks) {
        const int k0 = ks * 32 + lq * 8;
        bf16x8 a[4];
#pragma unroll
        for (int mf = 0; mf < 4; ++mf) {
            const float* xp = x + (long)(r0 + mf * 16 + l15) * 256 + k0;
            float4 u = *(const float4*)xp;
            float4 v = *(const float4*)(xp + 4);
            bf16x8 t;
            t[0] = f2bf(u.x); t[1] = f2bf(u.y); t[2] = f2bf(u.z); t[3] = f2bf(u.w);
            t[4] = f2bf(v.x); t[5] = f2bf(v.y); t[6] = f2bf(v.z); t[7] = f2bf(v.w);
            a[mf] = t;
        }
#pragma unroll
        for (int nf = 0; nf < 6; ++nf) {
            const int n = wave * 96 + nf * 16 + l15;
            bf16x8 b = *(const bf16x8*)(wt + n * 256 + k0);
#pragma unroll
            for (int mf = 0; mf < 4; ++mf) acc[mf][nf] = MFMA(a[mf], b, acc[mf][nf]);
        }
    }
#pragma unroll
    for (int nf = 0; nf < 6; ++nf) {
        const int col = wave * 96 + nf * 16 + l15;
        const float bias = (col < 128) ? bk[col] : ((col < 256) ? bv[col - 128] : bq[col - 256]);
#pragma unroll
        for (int mf = 0; mf < 4; ++mf) {
#pragma unroll
            for (int rr = 0; rr < 4; ++rr) {
                float v = acc[mf][nf][rr] + bias;
                v = (v > 0.f) ? v : (__expf(v) - 1.f);
                kvq[(long)(r0 + mf * 16 + lq * 4 + rr) * 384 + col] = f2bf(v);
            }
        }
    }
}

// ---------------------------------------------------------------------------
// Small fp32 "A^T @ B" partial GEMM for P1/P2 (K=1024 reduction, out 1024x128).
template <int COLS>
__global__ __launch_bounds__(256) void pgemm_kernel(
    const void* __restrict__ Agv, const void* __restrict__ Bgv,
    const int lda, const int ldb, const int rchunks, const int rstride,
    float* __restrict__ part)
{
    __shared__ __align__(16) short As[128][72];
    __shared__ __align__(16) short Bs[COLS][72];
    const int tid = threadIdx.x;
    const int wave = tid >> 6, lane = tid & 63;
    const int l15 = lane & 15, lq = lane >> 4;
    const int mt = blockIdx.x, rs = blockIdx.y;
    const long b0 = (long)rs * rstride;
    constexpr int NCF = COLS / 16;
    constexpr int CPT = COLS / 8;

    f32x4 acc[2][NCF];
    for (int s = 0; s < 2; ++s)
        for (int c = 0; c < NCF; ++c) acc[s][c] = (f32x4){0.f, 0.f, 0.f, 0.f};

    const int sr  = (tid & 31) * 2;
    const int am0 = (tid >> 5) * 16;
    const int bc0 = (tid >> 5) * CPT;

    for (int ch = 0; ch < rchunks; ++ch) {
        const long rb = b0 + (long)ch * 64;
        {
            const float* p0 = (const float*)Agv + (rb + sr) * lda + mt * 128 + am0;
            const float* p1 = p0 + lda;
#pragma unroll
            for (int j = 0; j < 16; ++j)
                *(uint32_t*)&As[am0 + j][sr] = pack2(p0[j], p1[j]);
        }
        {
            const float* p0 = (const float*)Bgv + (rb + sr) * ldb + bc0;
            const float* p1 = p0 + ldb;
#pragma unroll
            for (int j = 0; j < CPT; ++j)
                *(uint32_t*)&Bs[bc0 + j][sr] = pack2(p0[j], p1[j]);
        }
        __syncthreads();
#pragma unroll
        for (int ks = 0; ks < 2; ++ks) {
            bf16x8 a0 = *(const bf16x8*)&As[wave * 32 + l15][ks * 32 + lq * 8];
            bf16x8 a1 = *(const bf16x8*)&As[wave * 32 + 16 + l15][ks * 32 + lq * 8];
#pragma unroll
            for (int cf = 0; cf < NCF; ++cf) {
                bf16x8 b = *(const bf16x8*)&Bs[cf * 16 + l15][ks * 32 + lq * 8];
                acc[0][cf] = MFMA(a0, b, acc[0][cf]);
                acc[1][cf] = MFMA(a1, b, acc[1][cf]);
            }
        }
        __syncthreads();
    }
    float* pp = part + (long)rs * 1024 * COLS;
#pragma unroll
    for (int s = 0; s < 2; ++s)
#pragma unroll
        for (int cf = 0; cf < NCF; ++cf)
#pragma unroll
            for (int rr = 0; rr < 4; ++rr) {
                const int m = mt * 128 + wave * 32 + s * 16 + lq * 4 + rr;
                pp[(long)m * COLS + cf * 16 + l15] = acc[s][cf][rr];
            }
}

// ---------------------------------------------------------------------------
__global__ void finp_kernel(const float* __restrict__ part, short* __restrict__ pt) {
    const int i = blockIdx.x * 256 + threadIdx.x;
    float s = 0.f;
#pragma unroll
    for (int k = 0; k < 8; ++k) s += part[k * 131072 + i];
    pt[i] = f2bf(s);
}

// ---------------------------------------------------------------------------
// Einsum GEMM: part[ks][m][c] = sum_{k in split ks} w[k][m] * kvq[k][c]
__global__ __launch_bounds__(256) void eins_kernel(
    const short* __restrict__ w,    // [32768][1024] bf16 (write_w)
    const short* __restrict__ kvq,  // [32768][384]  bf16 (key|val|qry)
    short* __restrict__ part)       // [32][1024][256] bf16 partials
{
    __shared__ __align__(16) short As[8192];  // 16 KB
    __shared__ __align__(16) short Bs[8192];  // 16 KB
    const int tid = threadIdx.x;
    const int wave = tid >> 6, lane = tid & 63;
    const int l15 = lane & 15, lq = lane >> 4;
    const int mt = blockIdx.x >> 1, ct = blockIdx.x & 1;
    const int ks = blockIdx.y;
    const long k0_blk = (long)ks * 1024;

    int aoff[4], boff[4];
    const short* ldsA[4];
    const short* ldsB[4];
#pragma unroll
    for (int q = 0; q < 4; ++q) {
        const int t = wave + q * 4;
        const int s = t * 8 + (lane >> 3);
        const int kl = (s & 15) * 4 + ((lane & 7) >> 1);
        const int m  = (s >> 4) * 16 + (lane & 1) * 8;
        aoff[q] = kl * 1024 + mt * 128 + m;
        boff[q] = kl * 384  + ct * 128 + m;
        ldsA[q] = &As[t * 512];
        ldsB[q] = &Bs[t * 512];
    }

    f32x4 acc[4][4];
    for (int i = 0; i < 4; ++i)
        for (int j = 0; j < 4; ++j) acc[i][j] = (f32x4){0.f, 0.f, 0.f, 0.f};

    const int wr = wave >> 1, wc = wave & 1;
    const unsigned trb  = lds_addr(As) + 2u * (l15 + lq * 64);
    const unsigned trbB = lds_addr(Bs) + 2u * (l15 + lq * 64);

    for (int ch = 0; ch < 16; ++ch) {
        const short* wa = w   + (k0_blk + ch * 64) * 1024;
        const short* kb = kvq + (k0_blk + ch * 64) * 384;
#pragma unroll
        for (int q = 0; q < 4; ++q) {
            GLDS(wa + aoff[q], ldsA[q]);
            GLDS(kb + boff[q], ldsB[q]);
        }
        __syncthreads();
#pragma unroll
        for (int kst = 0; kst < 2; ++kst) {
            s16x4 ah[4][2], bh[4][2];
#pragma unroll
            for (int f = 0; f < 4; ++f) {
#pragma unroll
                for (int h = 0; h < 2; ++h) {
                    ah[f][h] = trrd(trb  + 128u * ((wr * 4 + f) * 16 + kst * 8 + h * 4));
                    bh[f][h] = trrd(trbB + 128u * ((wc * 4 + f) * 16 + kst * 8 + h * 4));
                }
            }
            asm volatile("s_waitcnt lgkmcnt(0)" ::: "memory");
            __builtin_amdgcn_sched_barrier(0);
#pragma unroll
            for (int mf = 0; mf < 4; ++mf) {
                bf16x8 a = cat8(ah[mf][0], ah[mf][1]);
#pragma unroll
                for (int cf = 0; cf < 4; ++cf)
                    acc[mf][cf] = MFMA(a, cat8(bh[cf][0], bh[cf][1]), acc[mf][cf]);
            }
        }
        __syncthreads();
    }

    short* pp = part + ((long)ks * 1024 + mt * 128) * 256 + ct * 128;
#pragma unroll
    for (int mf = 0; mf < 4; ++mf)
#pragma unroll
        for (int cf = 0; cf < 4; ++cf)
#pragma unroll
            for (int rr = 0; rr < 4; ++rr) {
                const int m = wr * 64 + mf * 16 + lq * 4 + rr;
                const int c = wc * 64 + cf * 16 + l15;
                pp[(long)m * 256 + c] = f2bf(acc[mf][cf][rr]);
            }
}

// ---------------------------------------------------------------------------
__global__ void finmem_kernel(const short* __restrict__ part,
                              const float* __restrict__ km, const float* __restrict__ vm,
                              float* __restrict__ km_new, short* __restrict__ vmt) {
    const int m = blockIdx.x;      // 0..1023
    const int c = threadIdx.x;     // 0..255
    float s = 0.f;
#pragma unroll
    for (int k = 0; k < 32; ++k) s += bf2f(part[k * 262144 + m * 256 + c]);
    s *= (1.0f / 32768.0f);
    if (c < 128) {
        km_new[m * 128 + c] = km[m * 128 + c] + s;
    } else {
        const int v = c - 128;
        vmt[v * 1024 + m] = f2bf(vm[m * 128 + v] + s);
    }
}

// ---------------------------------------------------------------------------
// Fused score+softmax (+optional PV) kernels. Swapped-operand phase 1:
// D[n][b] so each lane's acc quad is contiguous in n -> ds_write_b64.
// Softmax: 16 lanes per row, lane owns 64 cols in 8x b128 chunks, 4-step shfl.
constexpr int LW = 1032;  // LDS row stride (shorts); 16B-aligned rows

template <int KOFF, int DOPV>
__global__ __launch_bounds__(256, 2) void smx_kernel(
    const short* __restrict__ kvq, const short* __restrict__ pt,
    const float* __restrict__ bias, const short* __restrict__ vmt,
    short* __restrict__ wout, float* __restrict__ out)
{
    __shared__ __align__(16) short L[32][LW];
    __shared__ float invs[32];
    const int tid = threadIdx.x;
    const int wave = tid >> 6, lane = tid & 63;
    const int l15 = lane & 15, lq = lane >> 4;
    const int r0 = blockIdx.x * 32;

    // ---- phase 1: logits^T tiles. A = pt rows (n), B = kvq rows (batch).
    bf16x8 qf[2][4];
#pragma unroll
    for (int bg = 0; bg < 2; ++bg)
#pragma unroll
        for (int ks = 0; ks < 4; ++ks)
            qf[bg][ks] = *(const bf16x8*)(kvq + (long)(r0 + bg * 16 + l15) * 384 + KOFF + ks * 32 + lq * 8);

    for (int nt = 0; nt < 16; ++nt) {
        const int n0 = wave * 256 + nt * 16;
        f32x4 c0 = {0.f, 0.f, 0.f, 0.f}, c1 = {0.f, 0.f, 0.f, 0.f};
#pragma unroll
        for (int ks = 0; ks < 4; ++ks) {
            bf16x8 a = *(const bf16x8*)(pt + (n0 + l15) * 128 + ks * 32 + lq * 8);
            c0 = MFMA(a, qf[0][ks], c0);
            c1 = MFMA(a, qf[1][ks], c1);
        }
        *(uint2*)&L[l15][n0 + lq * 4]      = (uint2){pack2(c0[0], c0[1]), pack2(c0[2], c0[3])};
        *(uint2*)&L[16 + l15][n0 + lq * 4] = (uint2){pack2(c1[0], c1[1]), pack2(c1[2], c1[3])};
    }
    __syncthreads();

    // ---- phase 2: softmax. 4 rows in flight per wave; lane l15 owns 64 cols.
#pragma unroll
    for (int rep = 0; rep < 2; ++rep) {
        const int row = wave * 8 + rep * 4 + lq;
        float v[64], gm[8];
#pragma unroll
        for (int g = 0; g < 8; ++g) {
            bf16x8 t = *(const bf16x8*)&L[row][g * 128 + l15 * 8];
            float4 b0 = *(const float4*)(bias + g * 128 + l15 * 8);
            float4 b1 = *(const float4*)(bias + g * 128 + l15 * 8 + 4);
            v[g*8+0] = bf2f(t[0]) + b0.x; v[g*8+1] = bf2f(t[1]) + b0.y;
            v[g*8+2] = bf2f(t[2]) + b0.z; v[g*8+3] = bf2f(t[3]) + b0.w;
            v[g*8+4] = bf2f(t[4]) + b1.x; v[g*8+5] = bf2f(t[5]) + b1.y;
            v[g*8+6] = bf2f(t[6]) + b1.z; v[g*8+7] = bf2f(t[7]) + b1.w;
            gm[g] = fmaxf(fmaxf(fmaxf(v[g*8+0], v[g*8+1]), fmaxf(v[g*8+2], v[g*8+3])),
                          fmaxf(fmaxf(v[g*8+4], v[g*8+5]), fmaxf(v[g*8+6], v[g*8+7])));
        }
        float mx = fmaxf(fmaxf(fmaxf(gm[0], gm[1]), fmaxf(gm[2], gm[3])),
                         fmaxf(fmaxf(gm[4], gm[5]), fmaxf(gm[6], gm[7])));
#pragma unroll
        for (int off = 8; off; off >>= 1) mx = fmaxf(mx, __shfl_xor(mx, off));
        float gs[8];
#pragma unroll
        for (int g = 0; g < 8; ++g) {
            float s = 0.f;
#pragma unroll
            for (int j = 0; j < 8; ++j) { v[g*8+j] = __expf(v[g*8+j] - mx); s += v[g*8+j]; }
            gs[g] = s;
        }
        float sum = ((gs[0]+gs[1]) + (gs[2]+gs[3])) + ((gs[4]+gs[5]) + (gs[6]+gs[7]));
#pragma unroll
        for (int off = 8; off; off >>= 1) sum += __shfl_xor(sum, off);
        const float inv = 1.f / sum;

        if constexpr (!DOPV) {
            // normalized write_w straight to global, 16B stores
#pragma unroll
            for (int g = 0; g < 8; ++g) {
                bf16x8 t;
#pragma unroll
                for (int j = 0; j < 8; ++j) t[j] = f2bf(v[g*8+j] * inv);
                *(bf16x8*)(wout + (long)(r0 + row) * 1024 + g * 128 + l15 * 8) = t;
            }
        } else {
            // unnormalized exp back to LDS; defer scaling to the PV epilogue
#pragma unroll
            for (int g = 0; g < 8; ++g) {
                bf16x8 t;
#pragma unroll
                for (int j = 0; j < 8; ++j) t[j] = f2bf(v[g*8+j]);
                *(bf16x8*)&L[row][g * 128 + l15 * 8] = t;
            }
            if (l15 == 0) invs[row] = inv;
        }
    }

    if constexpr (DOPV) {
        __syncthreads();
        // PV: out[32 x 128] = P @ vmt^T; wave owns 2 col-tiles (32 v-cols).
        f32x4 acc[2][2];
        for (int i = 0; i < 2; ++i)
            for (int j = 0; j < 2; ++j) acc[i][j] = (f32x4){0.f, 0.f, 0.f, 0.f};
        for (int ks = 0; ks < 32; ++ks) {
            bf16x8 a0 = *(const bf16x8*)&L[l15][ks * 32 + lq * 8];
            bf16x8 a1 = *(const bf16x8*)&L[16 + l15][ks * 32 + lq * 8];
#pragma unroll
            for (int nf = 0; nf < 2; ++nf) {
                const int n = (wave * 2 + nf) * 16 + l15;
                bf16x8 b = *(const bf16x8*)(vmt + n * 1024 + ks * 32 + lq * 8);
                acc[0][nf] = MFMA(a0, b, acc[0][nf]);
                acc[1][nf] = MFMA(a1, b, acc[1][nf]);
            }
        }
#pragma unroll
        for (int mf = 0; mf < 2; ++mf)
#pragma unroll
            for (int nf = 0; nf < 2; ++nf)
#pragma unroll
                for (int rr = 0; rr < 4; ++rr) {
                    const int row = mf * 16 + lq * 4 + rr;
                    const int col = (wave * 2 + nf) * 16 + l15;
                    out[(long)(r0 + row) * 128 + col] = acc[mf][nf][rr] * invs[row];
                }
    }
}

// ---------------------------------------------------------------------------
extern "C" void kernel_launch(void* const* d_in, const int* in_sizes, int n_in,
                              void* d_out, int out_size, void* d_ws, size_t ws_size,
                              hipStream_t stream)
{
    const float* x   = (const float*)d_in[0];
    const float* Wk  = (const float*)d_in[1];
    const float* bk  = (const float*)d_in[2];
    const float* Wv  = (const float*)d_in[3];
    const float* bv  = (const float*)d_in[4];
    const float* Wq  = (const float*)d_in[5];
    const float* bq  = (const float*)d_in[6];
    const float* Wwr = (const float*)d_in[7];
    const float* bwr = (const float*)d_in[8];
    const float* Wrd = (const float*)d_in[9];
    const float* brd = (const float*)d_in[10];
    const float* km  = (const float*)d_in[11];
    const float* vm  = (const float*)d_in[12];
    float* out = (float*)d_out;

    char* ws = (char*)d_ws;
    short* kvq  = (short*)(ws + 0);           // 32768*384*2  = 25165824
    short* w    = (short*)(ws + 25165824);    // 32768*1024*2 = 67108864
    float* part = (float*)(ws + 92274688);    // 16 MB scratch
    short* p1t  = (short*)(ws + 109051904);   // 262144
    short* p2t  = (short*)(ws + 109314048);   // 262144
    float* kmn  = (float*)(ws + 109576192);   // 524288
    short* vmt  = (short*)(ws + 110100480);   // 262144
    short* wt   = (short*)(ws + 110362624);   // 196608  -> total 110559232
    if (ws_size < 110559232u) return;

    kw_kernel<<<384, 256, 0, stream>>>(Wk, Wv, Wq, wt);
    proj_kernel<<<512, 256, 0, stream>>>(x, wt, bk, bv, bq, kvq);
    // P1 = key_memory^T @ Wwr  (stored transposed [n][k])
    pgemm_kernel<128><<<dim3(8, 8), 256, 0, stream>>>(Wwr, km, 1024, 128, 2, 128, part);
    finp_kernel<<<512, 256, 0, stream>>>(part, p1t);
    // write_w = softmax(key @ P1 + bwr)
    smx_kernel<0, 0><<<1024, 256, 0, stream>>>(kvq, p1t, bwr, nullptr, w, nullptr);
    // einsum updates: [1024 x 256] = write_w^T @ [key|val]
    eins_kernel<<<dim3(16, 32), 256, 0, stream>>>(w, kvq, (short*)part);
    finmem_kernel<<<1024, 256, 0, stream>>>((const short*)part, km, vm, kmn, vmt);
    // P2 = key_mem_new^T @ Wrd
    pgemm_kernel<128><<<dim3(8, 8), 256, 0, stream>>>(Wrd, kmn, 1024, 128, 2, 128, part);
    finp_kernel<<<512, 256, 0, stream>>>(part, p2t);
    // read path fused: softmax(qry @ P2 + brd) @ val_mem_new
    smx_kernel<256, 1><<<1024, 256, 0, stream>>>(kvq, p2t, brd, vmt, nullptr, out);
}